// Round 1
// baseline (900.805 us; speedup 1.0000x reference)
//
#include <hip/hip_runtime.h>
#include <hip/hip_bf16.h>
#include <math.h>

// Problem constants
#define N_TOK   2048      // B*L = 32*64
#define HDIM    512
#define HHALF   256       // H/2
#define QDIM    1024      // 2*H
#define KDIM    256
#define HALF    128
#define HEADS   4
#define KNN     32
#define SUB     512
#define NROWS   8192      // N_TOK * HEADS (batchnorm rows)

// ---------------------------------------------------------------------------
// Generic NT GEMM tile: C[m][n] = sum_k A[m][k] * B[n][k] (+bias, relu)
// 64x64 tile, 256 threads, 4x4 microtile, BK=16.
// ---------------------------------------------------------------------------
__device__ __forceinline__ void gemm_tile_nt(
    const float* __restrict__ A, int lda,
    const float* __restrict__ B, int ldb,
    float* __restrict__ C, int ldc,
    int K, const float* __restrict__ bias, bool relu,
    int m0, int n0)
{
    __shared__ float As[16][68];
    __shared__ float Bs[16][68];
    int tid = threadIdx.x;
    int tx = tid & 15;        // n-dir
    int ty = tid >> 4;        // m-dir
    int lr = tid >> 2;        // 0..63: row within tile for loads
    int lc = (tid & 3) * 4;   // 0,4,8,12: k within K-tile for loads

    float acc[4][4] = {};

    for (int k0 = 0; k0 < K; k0 += 16) {
        float4 a = *(const float4*)(A + (size_t)(m0 + lr) * lda + k0 + lc);
        float4 b = *(const float4*)(B + (size_t)(n0 + lr) * ldb + k0 + lc);
        As[lc + 0][lr] = a.x; As[lc + 1][lr] = a.y;
        As[lc + 2][lr] = a.z; As[lc + 3][lr] = a.w;
        Bs[lc + 0][lr] = b.x; Bs[lc + 1][lr] = b.y;
        Bs[lc + 2][lr] = b.z; Bs[lc + 3][lr] = b.w;
        __syncthreads();
#pragma unroll
        for (int k = 0; k < 16; ++k) {
            float4 av = *(const float4*)&As[k][ty * 4];
            float4 bv = *(const float4*)&Bs[k][tx * 4];
            acc[0][0] = fmaf(av.x, bv.x, acc[0][0]);
            acc[0][1] = fmaf(av.x, bv.y, acc[0][1]);
            acc[0][2] = fmaf(av.x, bv.z, acc[0][2]);
            acc[0][3] = fmaf(av.x, bv.w, acc[0][3]);
            acc[1][0] = fmaf(av.y, bv.x, acc[1][0]);
            acc[1][1] = fmaf(av.y, bv.y, acc[1][1]);
            acc[1][2] = fmaf(av.y, bv.z, acc[1][2]);
            acc[1][3] = fmaf(av.y, bv.w, acc[1][3]);
            acc[2][0] = fmaf(av.z, bv.x, acc[2][0]);
            acc[2][1] = fmaf(av.z, bv.y, acc[2][1]);
            acc[2][2] = fmaf(av.z, bv.z, acc[2][2]);
            acc[2][3] = fmaf(av.z, bv.w, acc[2][3]);
            acc[3][0] = fmaf(av.w, bv.x, acc[3][0]);
            acc[3][1] = fmaf(av.w, bv.y, acc[3][1]);
            acc[3][2] = fmaf(av.w, bv.z, acc[3][2]);
            acc[3][3] = fmaf(av.w, bv.w, acc[3][3]);
        }
        __syncthreads();
    }

    // Epilogue
    float4 bb = make_float4(0.f, 0.f, 0.f, 0.f);
    if (bias) {
        bb.x = bias[n0 + tx * 4 + 0];
        bb.y = bias[n0 + tx * 4 + 1];
        bb.z = bias[n0 + tx * 4 + 2];
        bb.w = bias[n0 + tx * 4 + 3];
    }
#pragma unroll
    for (int i = 0; i < 4; ++i) {
        int m = m0 + ty * 4 + i;
        float4 r;
        r.x = acc[i][0] + bb.x;
        r.y = acc[i][1] + bb.y;
        r.z = acc[i][2] + bb.z;
        r.w = acc[i][3] + bb.w;
        if (relu) {
            r.x = fmaxf(r.x, 0.f); r.y = fmaxf(r.y, 0.f);
            r.z = fmaxf(r.z, 0.f); r.w = fmaxf(r.w, 0.f);
        }
        *(float4*)(C + (size_t)m * ldc + n0 + tx * 4) = r;
    }
}

__global__ __launch_bounds__(256) void gemm_nt_kernel(
    const float* __restrict__ A, int lda,
    const float* __restrict__ B, int ldb,
    float* __restrict__ C, int ldc,
    int K, const float* __restrict__ bias, int relu)
{
    gemm_tile_nt(A, lda, B, ldb, C, ldc, K, bias, relu != 0,
                 blockIdx.x * 64, blockIdx.y * 64);
}

// Batched score GEMM: z = head*2 + half
// s_half[n][head][k] = sum_d qn[n][head*256 + half*128 + d] * keys[head][half][k][d]
__global__ __launch_bounds__(256) void score_kernel(
    const float* __restrict__ q, const float* __restrict__ keys,
    float* __restrict__ s1, float* __restrict__ s2)
{
    int z = blockIdx.z;
    int hh = z >> 1;
    int half = z & 1;
    const float* A = q + hh * KDIM + half * HALF;    // lda = 1024
    const float* B = keys + (size_t)z * SUB * HALF;  // ldb = 128
    float* C = (half ? s2 : s1) + hh * SUB;          // ldc = HEADS*SUB = 2048
    gemm_tile_nt(A, QDIM, B, HALF, C, HEADS * SUB, HALF, nullptr, false,
                 blockIdx.x * 64, blockIdx.y * 64);
}

// ---------------------------------------------------------------------------
// BatchNorm: stats over flat (8192, 256), deterministic two-stage
// ---------------------------------------------------------------------------
__global__ __launch_bounds__(256) void bnstat_kernel(
    const float* __restrict__ q, float* __restrict__ partial)
{
    int c = threadIdx.x;
    int b = blockIdx.x;                 // 256 blocks, 32 rows each
    const float* base = q + (size_t)b * 32 * KDIM;
    float s = 0.f, s2 = 0.f;
#pragma unroll 8
    for (int r = 0; r < 32; ++r) {
        float v = base[r * KDIM + c];
        s += v;
        s2 = fmaf(v, v, s2);
    }
    partial[b * KDIM + c] = s;
    partial[256 * KDIM + b * KDIM + c] = s2;
}

__global__ __launch_bounds__(256) void bnfinal_kernel(
    const float* __restrict__ partial,
    const float* __restrict__ gamma, const float* __restrict__ beta,
    float* __restrict__ scsh)
{
    int c = threadIdx.x;
    float s = 0.f, s2 = 0.f;
    for (int b = 0; b < 256; ++b) {
        s += partial[b * KDIM + c];
        s2 += partial[256 * KDIM + b * KDIM + c];
    }
    float mean = s * (1.f / (float)NROWS);
    float var = s2 * (1.f / (float)NROWS) - mean * mean;
    float rstd = rsqrtf(var + 1e-5f);
    float sc = rstd * gamma[c];
    scsh[c] = sc;
    scsh[KDIM + c] = beta[c] - mean * sc;
}

__global__ __launch_bounds__(256) void bnapply_kernel(
    float* __restrict__ q, const float* __restrict__ scsh)
{
    int c = threadIdx.x;
    float sc = scsh[c];
    float sh = scsh[KDIM + c];
    size_t base = (size_t)blockIdx.x * 1024 + c;   // 4 flat rows of 256
#pragma unroll
    for (int r = 0; r < 4; ++r) {
        float v = q[base + r * KDIM];
        q[base + r * KDIM] = fmaf(v, sc, sh);
    }
}

// ---------------------------------------------------------------------------
// Top-k: one wave (64 threads) per (n, head) task.
// Stage 1: top-32 of 512 (twice, iterative wave argmax w/ removal).
// Stage 2: top-32 of 1024 pairwise sums, then softmax.
// Only the SET of selected elements matters downstream (softmax + weighted
// sum are permutation-invariant), ties measure-zero on random data.
// ---------------------------------------------------------------------------
__global__ __launch_bounds__(64) void topk_kernel(
    const float* __restrict__ s1, const float* __restrict__ s2,
    int* __restrict__ out_idx, float* __restrict__ out_w)
{
    const float NEG = -3.0e38f;
    int task = blockIdx.x;       // n*HEADS + h
    int lane = threadIdx.x;
    __shared__ float ts1[KNN]; __shared__ int ti1[KNN];
    __shared__ float ts2[KNN]; __shared__ int ti2[KNN];
    __shared__ float scv[KNN]; __shared__ int scp[KNN];

    for (int src = 0; src < 2; ++src) {
        const float* base = (src ? s2 : s1) + (size_t)task * SUB;
        float v[8];
#pragma unroll
        for (int i = 0; i < 8; ++i) v[i] = base[lane + 64 * i];
        float* tsv = src ? ts2 : ts1;
        int*   tsi = src ? ti2 : ti1;
        for (int t = 0; t < KNN; ++t) {
            float best = v[0]; int bi = 0;
#pragma unroll
            for (int i = 1; i < 8; ++i)
                if (v[i] > best) { best = v[i]; bi = i; }
            float bv = best;
            int bg = lane + 64 * bi;
#pragma unroll
            for (int off = 32; off; off >>= 1) {
                float ov = __shfl_xor(bv, off);
                int og = __shfl_xor(bg, off);
                if (ov > bv || (ov == bv && og < bg)) { bv = ov; bg = og; }
            }
            if (lane == 0) { tsv[t] = bv; tsi[t] = bg; }
            if (lane == (bg & 63)) v[bg >> 6] = NEG;
        }
    }
    __syncthreads();

    // Stage 2: 1024 pairwise sums, 16 per lane
    float cv[16];
#pragma unroll
    for (int t = 0; t < 16; ++t) {
        int p = lane + 64 * t;
        cv[t] = ts1[p >> 5] + ts2[p & 31];
    }
    for (int t = 0; t < KNN; ++t) {
        float best = cv[0]; int bi = 0;
#pragma unroll
        for (int i = 1; i < 16; ++i)
            if (cv[i] > best) { best = cv[i]; bi = i; }
        float bv = best;
        int bp = lane + 64 * bi;
#pragma unroll
        for (int off = 32; off; off >>= 1) {
            float ov = __shfl_xor(bv, off);
            int op = __shfl_xor(bp, off);
            if (ov > bv || (ov == bv && op < bp)) { bv = ov; bp = op; }
        }
        if (lane == 0) { scv[t] = bv; scp[t] = bp; }
        if (lane == (bp & 63)) cv[bp >> 6] = NEG;
    }
    __syncthreads();

    // Softmax over the 32 winners (scv[0] is the max — extracted first)
    float m = scv[0];
    float e = (lane < KNN) ? expf(scv[lane] - m) : 0.f;
    float ssum = e;
#pragma unroll
    for (int off = 32; off; off >>= 1) ssum += __shfl_xor(ssum, off);

    if (lane < KNN) {
        int p = scp[lane];
        int i = p >> 5, j = p & 31;
        int gidx = ti1[i] * SUB + ti2[j];
        int n = task >> 2, h = task & 3;
        out_idx[n * (HEADS * KNN) + h * KNN + lane] = gidx;
        out_w[n * (HEADS * KNN) + h * KNN + lane] = e / ssum;
    }
}

// ---------------------------------------------------------------------------
// Gather: rows[n][:] = sum_k w[n][k] * values[idx[n][k]][:]
// Block per token, 256 threads, float2 per thread (512 cols).
// ---------------------------------------------------------------------------
__global__ __launch_bounds__(256) void gather_kernel(
    const float* __restrict__ values, const int* __restrict__ idx,
    const float* __restrict__ w, float* __restrict__ rows)
{
    int n = blockIdx.x;
    int tid = threadIdx.x;
    __shared__ int sidx[HEADS * KNN];
    __shared__ float sw[HEADS * KNN];
    if (tid < HEADS * KNN) {
        sidx[tid] = idx[n * (HEADS * KNN) + tid];
        sw[tid] = w[n * (HEADS * KNN) + tid];
    }
    __syncthreads();
    const float2* vv = (const float2*)values;
    float2 acc = make_float2(0.f, 0.f);
#pragma unroll 4
    for (int k = 0; k < HEADS * KNN; ++k) {
        float2 v = vv[(size_t)sidx[k] * (HDIM / 2) + tid];
        float wk = sw[k];
        acc.x = fmaf(wk, v.x, acc.x);
        acc.y = fmaf(wk, v.y, acc.y);
    }
    ((float2*)rows)[(size_t)n * (HDIM / 2) + tid] = acc;
}

// out[b][c] = sum_l rows[b*64+l][c]
__global__ __launch_bounds__(512) void reduce_kernel(
    const float* __restrict__ rows, float* __restrict__ out)
{
    int b = blockIdx.x;
    int c = threadIdx.x;
    float s = 0.f;
    for (int l = 0; l < 64; ++l)
        s += rows[(size_t)(b * 64 + l) * HDIM + c];
    out[b * HDIM + c] = s;
}

// ---------------------------------------------------------------------------
extern "C" void kernel_launch(void* const* d_in, const int* in_sizes, int n_in,
                              void* d_out, int out_size, void* d_ws, size_t ws_size,
                              hipStream_t stream)
{
    const float* x      = (const float*)d_in[0];  // (32,64,512)
    const float* w1     = (const float*)d_in[1];  // (256,512)
    const float* b1     = (const float*)d_in[2];  // (256)
    const float* w2     = (const float*)d_in[3];  // (1024,256)
    const float* b2     = (const float*)d_in[4];  // (1024)
    const float* gamma  = (const float*)d_in[5];  // (256)
    const float* beta   = (const float*)d_in[6];  // (256)
    const float* keys   = (const float*)d_in[7];  // (4,2,512,128)
    const float* values = (const float*)d_in[8];  // (262144,512)
    float* out = (float*)d_out;                   // (32,512)

    // Workspace layout (floats). Total ~50.9 MB.
    float* ws = (float*)d_ws;
    float* h       = ws;                        // 2048*256   = 524288
    float* q       = h + N_TOK * HHALF;         // 2048*1024  = 2097152
    float* partial = q + N_TOK * QDIM;          // 2*256*256  = 131072
    float* scsh    = partial + 2 * 256 * KDIM;  // 512
    float* s1      = scsh + 2 * KDIM;           // 2048*4*512 = 4194304
    float* s2      = s1 + (size_t)N_TOK * HEADS * SUB;
    int*   tidx    = (int*)(s2 + (size_t)N_TOK * HEADS * SUB); // 262144 ints
    float* tw      = (float*)(tidx + N_TOK * HEADS * KNN);     // 262144
    float* rows    = tw + N_TOK * HEADS * KNN;  // 2048*512 = 1048576

    // 1) h = relu(x @ w1^T + b1): M=2048, N=256, K=512
    gemm_nt_kernel<<<dim3(N_TOK / 64, HHALF / 64), 256, 0, stream>>>(
        x, HDIM, w1, HDIM, h, HHALF, HDIM, b1, 1);

    // 2) q = h @ w2^T + b2: M=2048, N=1024, K=256
    gemm_nt_kernel<<<dim3(N_TOK / 64, QDIM / 64), 256, 0, stream>>>(
        h, HHALF, w2, HHALF, q, QDIM, HHALF, b2, 0);

    // 3) BatchNorm over flat (8192, 256)
    bnstat_kernel<<<256, 256, 0, stream>>>(q, partial);
    bnfinal_kernel<<<1, 256, 0, stream>>>(partial, gamma, beta, scsh);
    bnapply_kernel<<<N_TOK, 256, 0, stream>>>(q, scsh);

    // 4) Scores: 8 batched NT-GEMMs, M=2048, N=512, K=128
    score_kernel<<<dim3(N_TOK / 64, SUB / 64, HEADS * 2), 256, 0, stream>>>(
        q, keys, s1, s2);

    // 5) Top-k + softmax: one wave per (n, head)
    topk_kernel<<<N_TOK * HEADS, 64, 0, stream>>>(s1, s2, tidx, tw);

    // 6) Weighted gather from values
    gather_kernel<<<N_TOK, 256, 0, stream>>>(values, tidx, tw, rows);

    // 7) Reduce over L=64
    reduce_kernel<<<32, 512, 0, stream>>>(rows, out);
}